// Round 2
// baseline (350.012 us; speedup 1.0000x reference)
//
#include <hip/hip_runtime.h>
#include <stdint.h>

typedef float f32x4 __attribute__((ext_vector_type(4)));
typedef float f32x16 __attribute__((ext_vector_type(16)));
typedef __bf16 bf16x8 __attribute__((ext_vector_type(8)));
typedef unsigned short u16;
typedef unsigned int u32;

#define INVT 14.285714285714286f   // 1/0.07 ; also the fixed LSE max bound (cos<=1)
#define L2E  1.4426950408889634f

__device__ __forceinline__ u16 f2bf(float f) {
  u32 u = __float_as_uint(f);
  u32 r = (u + 0x7fffu + ((u >> 16) & 1u)) >> 16;
  return (u16)r;
}
__device__ __forceinline__ float bf2f(u16 h) { return __uint_as_float(((u32)h) << 16); }

// async global->LDS, 16B per lane (lane i lands at base + i*16)
__device__ __forceinline__ void g2l16(const void* g, void* l) {
  auto gp = reinterpret_cast<__attribute__((address_space(1))) uint32_t*>(
      reinterpret_cast<uintptr_t>(g));
  auto lp = reinterpret_cast<__attribute__((address_space(3))) uint32_t*>(
      reinterpret_cast<uintptr_t>(l));
  __builtin_amdgcn_global_load_lds(gp, lp, 16, 0, 0);
}

// ---------- fused prep: fp32->bf16 convert of both inputs + W0/W1/W2 transposes ----------
// flat grid role split: [0,16384) cvt; [16384,18432) W0/W1 transpose; [18432,18496) W2.
__global__ __launch_bounds__(256) void k_prep(const float* __restrict__ in1,
                                              const float* __restrict__ in2,
                                              u16* __restrict__ Xb,
                                              const float* __restrict__ w0, u16* __restrict__ w0t,
                                              const float* __restrict__ w1, u16* __restrict__ w1t,
                                              const float* __restrict__ w2, u16* __restrict__ w2t) {
  const int bid = blockIdx.x;
  if (bid < 16384) {
    int i = (bid * 256 + threadIdx.x) * 4;
    float4 v;
    if (i < 8388608) v = *(const float4*)(in1 + i);
    else             v = *(const float4*)(in2 + (i - 8388608));
    ushort4 p;
    p.x = f2bf(v.x); p.y = f2bf(v.y); p.z = f2bf(v.z); p.w = f2bf(v.w);
    *(ushort4*)(Xb + i) = p;
    return;
  }
  __shared__ float t[64][65];
  const float* in; u16* out; int R, C, r0, c0;
  if (bid < 18432) {
    const int f = bid - 16384;
    const int z = f >> 10, rem = f & 1023;
    in = z ? w1 : w0; out = z ? w1t : w0t; R = 2048; C = 2048;
    r0 = (rem >> 5) * 64; c0 = (rem & 31) * 64;
  } else {
    const int f = bid - 18432;
    in = w2; out = w2t; R = 2048; C = 128;
    r0 = (f >> 1) * 64; c0 = (f & 1) * 64;
  }
#pragma unroll
  for (int p = 0; p < 16; ++p) {
    int idx = p * 256 + threadIdx.x;
    int r = idx >> 6, c = idx & 63;
    t[r][c] = in[(size_t)(r0 + r) * C + (c0 + c)];
  }
  __syncthreads();
#pragma unroll
  for (int p = 0; p < 16; ++p) {
    int idx = p * 256 + threadIdx.x;
    int c = idx >> 6, r = idx & 63;
    out[(size_t)(c0 + c) * R + (r0 + r)] = f2bf(t[r][c]);
  }
}

// ---------- bf16 GEMM: C = op(A @ Bt^T + bias) ----------
// Round-7: 256x256 4-phase schedule with LANE-LINEAR fragment layout.
// BM=BN=256, BK=64, 512 threads = 8 waves (2M x 4N), wave tile 128x64
// (4x2 of 32x32x16 MFMA). LDS 128 KiB = 2 bufs x [A-h0|A-h1|B-h0|B-h1]
// 16KB half-tiles. Each half-tile is stored fragment-major:
//   [k16 slice][row-group rg (32 rows)][c0][lm]  (1KB per (k16,rg) sub-block)
// so every ds_read_b128 fragment read is addr = const + lane*16 -> perfectly
// lane-linear, ZERO bank conflicts under any HW lane grouping (the round-1
// XOR swizzle measured exactly 4.0 conflict-cycles per read; that drain was
// 770cy/phase CU-serial vs MFMA's 516cy -> the real bottleneck).
// Staging realizes this layout by pre-permuting the per-lane GLOBAL source
// address (global_load_lds dest is always base+lane*16): lane (c0,lm) of
// wave w fetches A[m0 + w*32 + lm][t*64 + h*32 + k16*16 + c0*8]. Same data
// per lane as round-1 -> bitwise-identical MFMA inputs.
// Waits: vmcnt(4) at phases 1,3 (prefetch distance 2-3 phases, ~1500cy
// slack); drains vmcnt(0) on the last tile (fixes latent last-tile race).
__global__ __launch_bounds__(512, 2) void k_gemm(const u16* __restrict__ A, const u16* __restrict__ Bt,
                                                 const float* __restrict__ bias, u16* __restrict__ C,
                                                 int M, int N, int K, int relu) {
  __shared__ __align__(16) u16 sm[65536];  // 128 KiB
  const int tid = threadIdx.x;
  const int l = tid & 63, w = tid >> 6;
  const int wm = w >> 2, wn = w & 3;       // 2 (M) x 4 (N)
  const int lm = l & 31, c0 = l >> 5;
  const int m0 = blockIdx.y * 256, n0 = blockIdx.x * 256;

  // per-thread global staging base: row = blockrow + w*32 + lm, col = c0*8 elems
  const char* gA = (const char*)(A + (size_t)(m0 + w * 32 + lm) * K + c0 * 8);
  const char* gB = (const char*)(Bt + (size_t)(n0 + w * 32 + lm) * K + c0 * 8);

  auto issue_half = [&](int t, int part, int stg) {
    // part: 0 = A k-half0, 1 = B k-half0, 2 = A k-half1, 3 = B k-half1
    const int h = part >> 1, isB = part & 1;
    const char* g = (isB ? gB : gA) + (size_t)t * 128 + h * 64;
    char* lb = (char*)sm + stg * 65536 + isB * 32768 + h * 16384 + w * 1024 + l * 16;
    g2l16(g, lb);              // k16=0 sub-blocks
    g2l16(g + 32, lb + 8192);  // k16=1 sub-blocks
  };

  f32x16 acc[4][2] = {};
  const int NT = K >> 6;

  // prologue: tile 0's 4 half-tiles; vmcnt(4) -> K-half0 of A and B landed
  issue_half(0, 0, 0); issue_half(0, 1, 0); issue_half(0, 2, 0); issue_half(0, 3, 0);
  asm volatile("s_waitcnt vmcnt(4)" ::: "memory");
  asm volatile("s_barrier" ::: "memory");

  for (int kt = 0; kt < NT; ++kt) {
    const u16* bcur = sm + (kt & 1) * 32768;   // u16 units
    const int nstg = (kt & 1) ^ 1;
    const bool pf = (kt + 1) < NT;

#pragma unroll
    for (int k = 0; k < 4; ++k) {              // 4 phases, K=16 each
      const u16* As = bcur + (k >> 1) * 8192;           // A half-tile (u16 units)
      const u16* Bs = bcur + 16384 + (k >> 1) * 8192;   // B half-tile
      const int fb = (k & 1) * 4096 + c0 * 256 + lm * 8;  // lane-linear frag base
      bf16x8 a4[4], b2[2];
#pragma unroll
      for (int fm = 0; fm < 4; ++fm)
        a4[fm] = *(const bf16x8*)(As + fb + (wm * 4 + fm) * 512);
#pragma unroll
      for (int fn = 0; fn < 2; ++fn)
        b2[fn] = *(const bf16x8*)(Bs + fb + (wn * 2 + fn) * 512);
      if (pf) issue_half(kt + 1, k, nstg);
      asm volatile("s_barrier" ::: "memory");
      asm volatile("s_waitcnt lgkmcnt(0)" ::: "memory");
      __builtin_amdgcn_s_setprio(1);
#pragma unroll
      for (int fm = 0; fm < 4; ++fm)
#pragma unroll
        for (int fn = 0; fn < 2; ++fn)
          acc[fm][fn] = __builtin_amdgcn_mfma_f32_32x32x16_bf16(a4[fm], b2[fn],
                                                                acc[fm][fn], 0, 0, 0);
      __builtin_amdgcn_s_setprio(0);
      if (k & 1) {
        if (pf) asm volatile("s_waitcnt vmcnt(4)" ::: "memory");
        else    asm volatile("s_waitcnt vmcnt(0)" ::: "memory");
      }
      asm volatile("s_barrier" ::: "memory");
    }
  }

  const int colb = n0 + wn * 64 + lm;
  const int rowb = m0 + wm * 128 + 4 * c0;
#pragma unroll
  for (int fn = 0; fn < 2; ++fn) {
    const float b = bias[colb + fn * 32];
#pragma unroll
    for (int fm = 0; fm < 4; ++fm)
#pragma unroll
      for (int g = 0; g < 4; ++g)
#pragma unroll
        for (int rr = 0; rr < 4; ++rr) {
          float v = acc[fm][fn][g * 4 + rr] + b;
          if (relu) v = fmaxf(v, 0.0f);
          C[(size_t)(rowb + fm * 32 + g * 8 + rr) * N + colb + fn * 32] = f2bf(v);
        }
  }
}

// ---------- split-K GEMM2 (N=128): 128x128 tile, 3-stage, 1 barrier/step ----------
__global__ __launch_bounds__(256, 2) void k_gemm_sk(const u16* __restrict__ A, const u16* __restrict__ Bt,
                                                    float* __restrict__ Ep, int K, int Ksplit) {
  __shared__ __align__(16) u16 sm[24576];
  const int tid = threadIdx.x;
  const int l = tid & 63, w = tid >> 6;
  const int wm = w >> 1, wn = w & 1;
  const int m0 = blockIdx.y * 128;
  const int split = blockIdx.x;
  const int k0s = split * Ksplit;

  const int kb = ((l & 3) ^ ((l >> 3) & 3)) * 16;
  const char* gA = (const char*)(A + (size_t)(m0 + w * 16 + (l >> 2)) * K + k0s) + kb;
  const char* gB = (const char*)(Bt + (size_t)(w * 16 + (l >> 2)) * K + k0s) + kb;
  const size_t radv = (size_t)64 * K * 2;

  auto issue = [&](int kcB, int stg) {
    char* base = (char*)sm + stg * 16384;
    char* dA = base + w * 1024 + l * 16;
    char* dB = base + 8192 + w * 1024 + l * 16;
    g2l16(gA + kcB, dA);
    g2l16(gA + radv + kcB, dA + 4096);
    g2l16(gB + kcB, dB);
    g2l16(gB + radv + kcB, dB + 4096);
  };

  const int lm = l & 31;
  const int c0 = l >> 5;
  const int sw = (lm >> 1) & 3;

  f32x16 acc[2][2] = {};

  auto compute = [&](int stg) {
    const u16* As = sm + stg * 8192;
    const u16* Bs = As + 4096;
#pragma unroll
    for (int t = 0; t < 2; ++t) {
      const int cc = (((t << 1) + c0) ^ sw) * 8;
      bf16x8 a2[2], b2[2];
#pragma unroll
      for (int fm = 0; fm < 2; ++fm) a2[fm] = *(const bf16x8*)(As + (wm * 64 + fm * 32 + lm) * 32 + cc);
#pragma unroll
      for (int fn = 0; fn < 2; ++fn) b2[fn] = *(const bf16x8*)(Bs + (wn * 64 + fn * 32 + lm) * 32 + cc);
#pragma unroll
      for (int fm = 0; fm < 2; ++fm)
#pragma unroll
        for (int fn = 0; fn < 2; ++fn)
          acc[fm][fn] = __builtin_amdgcn_mfma_f32_32x32x16_bf16(a2[fm], b2[fn],
                                                                acc[fm][fn], 0, 0, 0);
    }
  };

  const int NK = Ksplit >> 5;
  issue(0, 0);
  issue(64, 1);
  int st = 0;
  for (int kt = 0; kt < NK; ++kt) {
    if (kt + 1 < NK) asm volatile("s_waitcnt vmcnt(4)" ::: "memory");
    else             asm volatile("s_waitcnt vmcnt(0)" ::: "memory");
    asm volatile("s_barrier" ::: "memory");
    if (kt + 2 < NK) {
      int stp = st + 2; if (stp >= 3) stp -= 3;
      issue((kt + 2) * 64, stp);
    }
    compute(st);
    ++st; if (st == 3) st = 0;
  }

  const int colb = wn * 64 + lm;
  const int rowb = m0 + wm * 64 + 4 * c0;
#pragma unroll
  for (int fn = 0; fn < 2; ++fn)
#pragma unroll
    for (int fm = 0; fm < 2; ++fm)
#pragma unroll
      for (int g = 0; g < 4; ++g)
#pragma unroll
        for (int rr = 0; rr < 4; ++rr)
          Ep[((size_t)split * 8192 + rowb + fm * 32 + g * 8 + rr) * 128 + colb + fn * 32] =
              acc[fm][fn][g * 4 + rr];
}

// ---------- sum split-K partials + bias, L2-normalize rows, write bf16 f ----------
__global__ __launch_bounds__(256) void k_norm(const float* __restrict__ Ep,
                                              const float* __restrict__ b2, u16* __restrict__ F) {
  const int l = threadIdx.x & 63, w = threadIdx.x >> 6;
  const int row = blockIdx.x * 4 + w;
  const float2* base = (const float2*)Ep + (size_t)row * 64 + l;
  float x = 0.f, y = 0.f;
#pragma unroll
  for (int s = 0; s < 4; ++s) {
    float2 t = base[(size_t)s * (8192 * 64)];
    x += t.x; y += t.y;
  }
  x += b2[l * 2]; y += b2[l * 2 + 1];
  float sq = x * x + y * y;
#pragma unroll
  for (int off = 1; off < 64; off <<= 1) sq += __shfl_xor(sq, off);
  const float inv = 1.0f / sqrtf(sq);
  F[(size_t)row * 128 + l * 2] = f2bf(x * inv);
  F[(size_t)row * 128 + l * 2 + 1] = f2bf(y * inv);
}

// ---------- fused sim GEMM + fixed-max sumexp, register-cached A ----------
__global__ __launch_bounds__(256, 2) void k_sim(const u16* __restrict__ F, float* __restrict__ Sp) {
  __shared__ __align__(16) u16 sm[32768];  // [B0 32KB][A/B1 32KB]
  const int tid = threadIdx.x;
  const int l = tid & 63, w = tid >> 6;
  const int wm = w >> 1, wn = w & 1;
  const int lm = l & 31, c0 = l >> 5;
  const int r0 = blockIdx.y * 128;
  const int cb0 = blockIdx.x * 1024;

  u16* B0 = sm;
  u16* AB1 = sm + 16384;

  const int srow0 = tid >> 4;
  const int schunk = tid & 15;
  auto stage = [&](const u16* src, u16* dst) {
#pragma unroll
    for (int j = 0; j < 8; ++j) {
      const int row = j * 16 + srow0;
      const int lc = schunk ^ (row & 7);
      g2l16((const char*)(src + (size_t)row * 128) + lc * 16,
            (char*)dst + j * 4096 + tid * 16);
    }
  };

  stage(F + (size_t)r0 * 128, AB1);
  asm volatile("s_waitcnt vmcnt(0)" ::: "memory");
  __syncthreads();

  bf16x8 a[2][8];
#pragma unroll
  for (int fm = 0; fm < 2; ++fm) {
    const int ra = wm * 64 + fm * 32 + lm;
#pragma unroll
    for (int kf = 0; kf < 8; ++kf)
      a[fm][kf] = *(const bf16x8*)(AB1 + ra * 128 + (((kf << 1) + c0) ^ (ra & 7)) * 8);
  }
  asm volatile("s_waitcnt lgkmcnt(0)" ::: "memory");

  stage(F + (size_t)cb0 * 128, B0);

  const float S2 = INVT * L2E;
  const int rB = wn * 64 + lm;
  f32x16 runS[2] = {};

#pragma unroll 1
  for (int p = 0; p < 8; ++p) {
    asm volatile("s_waitcnt vmcnt(0)" ::: "memory");
    asm volatile("s_barrier" ::: "memory");
    if (p < 7) stage(F + (size_t)(cb0 + (p + 1) * 128) * 128, (p & 1) ? B0 : AB1);
    const u16* Bs = (p & 1) ? AB1 : B0;

    f32x16 acc[2][2] = {};
#pragma unroll
    for (int kf = 0; kf < 8; ++kf) {
      const int kc = (kf << 1) + c0;
      bf16x8 b0v = *(const bf16x8*)(Bs + rB * 128 + (kc ^ (rB & 7)) * 8);
      bf16x8 b1v = *(const bf16x8*)(Bs + (rB + 32) * 128 + (kc ^ ((rB + 32) & 7)) * 8);
      acc[0][0] = __builtin_amdgcn_mfma_f32_32x32x16_bf16(a[0][kf], b0v, acc[0][0], 0, 0, 0);
      acc[0][1] = __builtin_amdgcn_mfma_f32_32x32x16_bf16(a[0][kf], b1v, acc[0][1], 0, 0, 0);
      acc[1][0] = __builtin_amdgcn_mfma_f32_32x32x16_bf16(a[1][kf], b0v, acc[1][0], 0, 0, 0);
      acc[1][1] = __builtin_amdgcn_mfma_f32_32x32x16_bf16(a[1][kf], b1v, acc[1][1], 0, 0, 0);
    }

    const int cp = cb0 + p * 128;
    if (cp == r0) {
#pragma unroll
      for (int fm = 0; fm < 2; ++fm)
#pragma unroll
        for (int fn = 0; fn < 2; ++fn) {
          const int rcol = wn * 64 + fn * 32 + lm;
#pragma unroll
          for (int r = 0; r < 16; ++r) {
            const int rrow = wm * 64 + fm * 32 + (r & 3) + 8 * (r >> 2) + 4 * c0;
            float e = exp2f(fmaf(acc[fm][fn][r], S2, -S2));
            if (rrow == rcol) e = 0.f;
            runS[fm][r] += e;
          }
        }
    } else {
#pragma unroll
      for (int fm = 0; fm < 2; ++fm)
#pragma unroll
        for (int fn = 0; fn < 2; ++fn)
#pragma unroll
          for (int r = 0; r < 16; ++r)
            runS[fm][r] += exp2f(fmaf(acc[fm][fn][r], S2, -S2));
    }
  }

#pragma unroll
  for (int fm = 0; fm < 2; ++fm)
#pragma unroll
    for (int r = 0; r < 16; ++r) {
      float s = runS[fm][r];
      s += __shfl_xor(s, 1);
      s += __shfl_xor(s, 2);
      s += __shfl_xor(s, 4);
      s += __shfl_xor(s, 8);
      s += __shfl_xor(s, 16);
      runS[fm][r] = s;
    }

  __syncthreads();
  float* red = (float*)sm;
  if (wn == 0) {
    if (lm == 0) {
#pragma unroll
      for (int fm = 0; fm < 2; ++fm)
#pragma unroll
        for (int r = 0; r < 16; ++r)
          red[wm * 64 + fm * 32 + (r & 3) + 8 * (r >> 2) + 4 * c0] = runS[fm][r];
    }
  }
  __syncthreads();
  if (wn == 1 && lm == 0) {
#pragma unroll
    for (int fm = 0; fm < 2; ++fm)
#pragma unroll
      for (int r = 0; r < 16; ++r) {
        const int rr = wm * 64 + fm * 32 + (r & 3) + 8 * (r >> 2) + 4 * c0;
        Sp[(size_t)blockIdx.x * 8192 + r0 + rr] = red[rr] + runS[fm][r];
      }
  }
}

// ---------- merge chunk partials, compute pos, reduce mean(lse - pos) ----------
__global__ __launch_bounds__(256) void k_combine(const float* __restrict__ Sp,
                                                 const u16* __restrict__ F,
                                                 float* __restrict__ out) {
  const int r = blockIdx.x * 256 + threadIdx.x;
  float S = 0.f;
#pragma unroll
  for (int c = 0; c < 8; ++c) S += Sp[c * 8192 + r];
  const float lse = INVT + logf(S);
  const int par = (r + 4096) & 8191;
  const bf16x8* a = (const bf16x8*)(F + (size_t)r * 128);
  const bf16x8* b = (const bf16x8*)(F + (size_t)par * 128);
  float dot = 0.f;
#pragma unroll
  for (int k = 0; k < 16; ++k) {
    bf16x8 va = a[k], vb = b[k];
#pragma unroll
    for (int j = 0; j < 8; ++j) dot = fmaf((float)va[j], (float)vb[j], dot);
  }
  float contrib = lse - dot * INVT;
#pragma unroll
  for (int off = 1; off < 64; off <<= 1) contrib += __shfl_xor(contrib, off);
  if ((threadIdx.x & 63) == 0) atomicAdd(out, contrib * (1.0f / 8192.0f));
}

extern "C" void kernel_launch(void* const* d_in, const int* in_sizes, int n_in,
                              void* d_out, int out_size, void* d_ws, size_t ws_size,
                              hipStream_t stream) {
  const float* input1 = (const float*)d_in[0];
  const float* input2 = (const float*)d_in[1];
  const float* W0 = (const float*)d_in[2];
  const float* b0 = (const float*)d_in[3];
  const float* W1 = (const float*)d_in[4];
  const float* b1 = (const float*)d_in[5];
  const float* W2 = (const float*)d_in[6];
  const float* b2 = (const float*)d_in[7];
  float* out = (float*)d_out;
  char* ws = (char*)d_ws;

  u16* Xb = (u16*)(ws + 0);              // [8192][2048] bf16; reused as H2
  u16* H1 = (u16*)(ws + 33554432);
  u16* W0T = (u16*)(ws + 67108864);
  u16* W1T = (u16*)(ws + 75497472);
  float* Ep = (float*)(ws + 67108864);   // [4][8192][128] fp32, overlays dead W0T/W1T
  u16* W2T = (u16*)(ws + 83886080);
  float* Sp = (float*)(ws + 83886080);   // [8][8192] fp32, overlays W2T after sk
  u16* Ff = (u16*)(ws + 84410368);
  u16* H2 = Xb;

  hipMemsetAsync(d_out, 0, sizeof(float), stream);
  k_prep<<<18496, 256, 0, stream>>>(input1, input2, Xb, W0, W0T, W1, W1T, W2, W2T);
  k_gemm<<<dim3(8, 32), 512, 0, stream>>>(Xb, W0T, b0, H1, 8192, 2048, 2048, 1);
  k_gemm<<<dim3(8, 32), 512, 0, stream>>>(H1, W1T, b1, H2, 8192, 2048, 2048, 0);
  k_gemm_sk<<<dim3(4, 64), 256, 0, stream>>>(H2, W2T, Ep, 2048, 512);
  k_norm<<<2048, 256, 0, stream>>>(Ep, b2, Ff);
  k_sim<<<dim3(8, 64), 256, 0, stream>>>(Ff, Sp);
  k_combine<<<32, 256, 0, stream>>>(Sp, Ff, out);
}

// Round 3
// 339.615 us; speedup vs baseline: 1.0306x; 1.0306x over previous
//
#include <hip/hip_runtime.h>
#include <stdint.h>

typedef float f32x4 __attribute__((ext_vector_type(4)));
typedef float f32x16 __attribute__((ext_vector_type(16)));
typedef __bf16 bf16x8 __attribute__((ext_vector_type(8)));
typedef unsigned short u16;
typedef unsigned int u32;

#define INVT 14.285714285714286f   // 1/0.07 ; also the fixed LSE max bound (cos<=1)
#define L2E  1.4426950408889634f

__device__ __forceinline__ u16 f2bf(float f) {
  u32 u = __float_as_uint(f);
  u32 r = (u + 0x7fffu + ((u >> 16) & 1u)) >> 16;
  return (u16)r;
}
__device__ __forceinline__ float bf2f(u16 h) { return __uint_as_float(((u32)h) << 16); }

// async global->LDS, 16B per lane (lane i lands at base + i*16)
__device__ __forceinline__ void g2l16(const void* g, void* l) {
  auto gp = reinterpret_cast<__attribute__((address_space(1))) uint32_t*>(
      reinterpret_cast<uintptr_t>(g));
  auto lp = reinterpret_cast<__attribute__((address_space(3))) uint32_t*>(
      reinterpret_cast<uintptr_t>(l));
  __builtin_amdgcn_global_load_lds(gp, lp, 16, 0, 0);
}

// ================= BLOCKED GLOBAL FORMAT =================
// For an MxK bf16 matrix (M mult of 32, K mult of 16):
//   elem (r, c) -> u16 offset  s*(M*16) + g*512 + c0*256 + lm*8 + e
//   with s = c>>4, g = r>>5, c0 = (c>>3)&1, lm = r&31, e = c&7.
// This is EXACTLY the k_gemm LDS image: staging becomes a contiguous
// 1KB-per-wave memcpy (global_load_lds dest = base+lane*16, source
// lane-linear too), and fragment ds_reads stay lane-linear (round-2
// verified: SQ_LDS_BANK_CONFLICT == 0). Round-1/2 proved you cannot have
// coalesced staging AND conflict-free reads with a row-major global
// layout; baking the LDS image into the producers gives both.

// ---------- fused prep ----------
// [0,8192): cvt in1/in2 f32 -> Xb blocked bf16 (unit u = bid*4+w: s=u&127, g=u>>7)
// [8192,12288): W0/W1 direct transpose -> blocked W0T/W1T
// [12288,12352): W2 tile transpose -> row-major W2T (gemm_sk unchanged)
__global__ __launch_bounds__(256) void k_prep(const float* __restrict__ in1,
                                              const float* __restrict__ in2,
                                              u16* __restrict__ Xb,
                                              const float* __restrict__ w0, u16* __restrict__ w0t,
                                              const float* __restrict__ w1, u16* __restrict__ w1t,
                                              const float* __restrict__ w2, u16* __restrict__ w2t) {
  const int bid = blockIdx.x;
  const int tid = threadIdx.x;
  if (bid < 8192) {
    const int l = tid & 63, w = tid >> 6;
    const int lm = l & 31, ch = l >> 5;
    const int u = bid * 4 + w;
    const int s = u & 127, g = u >> 7;       // g in [0,256): g<128 -> in1
    const float* src = (g < 128 ? in1 : in2) +
                       (size_t)((g & 127) * 32 + lm) * 2048 + s * 16 + ch * 8;
    float4 v0 = *(const float4*)src;
    float4 v1 = *(const float4*)(src + 4);
    uint4 o;
    o.x = (u32)f2bf(v0.x) | ((u32)f2bf(v0.y) << 16);
    o.y = (u32)f2bf(v0.z) | ((u32)f2bf(v0.w) << 16);
    o.z = (u32)f2bf(v1.x) | ((u32)f2bf(v1.y) << 16);
    o.w = (u32)f2bf(v1.z) | ((u32)f2bf(v1.w) << 16);
    *(uint4*)(Xb + (size_t)s * 131072 + g * 512 + l * 8) = o;
    return;
  }
  if (bid < 12288) {
    // W (2048x2048 f32, row-major [k][n]) -> WT blocked over (n rows, k cols)
    const int l = tid & 63, w = tid >> 6;
    const int lm = l & 31, ch = l >> 5;
    const int v = (bid - 8192) * 4 + w;
    const int z = v >> 13, u2 = v & 8191;
    const int s = u2 & 127, g = u2 >> 7;     // s: k-slab, g in [0,64)
    const float* Wm = z ? w1 : w0;
    u16* O = z ? w1t : w0t;
    const float* src = Wm + (size_t)(s * 16 + ch * 8) * 2048 + g * 32 + lm;
    float f0 = src[0];
    float f1 = src[2048];
    float f2 = src[2 * 2048];
    float f3 = src[3 * 2048];
    float f4 = src[4 * 2048];
    float f5 = src[5 * 2048];
    float f6 = src[6 * 2048];
    float f7 = src[7 * 2048];
    uint4 o;
    o.x = (u32)f2bf(f0) | ((u32)f2bf(f1) << 16);
    o.y = (u32)f2bf(f2) | ((u32)f2bf(f3) << 16);
    o.z = (u32)f2bf(f4) | ((u32)f2bf(f5) << 16);
    o.w = (u32)f2bf(f6) | ((u32)f2bf(f7) << 16);
    *(uint4*)(O + (size_t)s * 32768 + g * 512 + l * 8) = o;
    return;
  }
  // W2 tile transpose (row-major out, unchanged consumer: k_gemm_sk)
  __shared__ float t[64][65];
  const int f = bid - 12288;
  const float* in = w2;
  u16* out = w2t;
  const int C = 128, R = 2048;
  const int r0 = (f >> 1) * 64, c0t = (f & 1) * 64;
#pragma unroll
  for (int p = 0; p < 16; ++p) {
    int idx = p * 256 + tid;
    int r = idx >> 6, c = idx & 63;
    t[r][c] = in[(size_t)(r0 + r) * C + (c0t + c)];
  }
  __syncthreads();
#pragma unroll
  for (int p = 0; p < 16; ++p) {
    int idx = p * 256 + tid;
    int c = idx >> 6, r = idx & 63;
    out[(size_t)(c0t + c) * R + (r0 + r)] = f2bf(t[r][c]);
  }
}

// ---------- bf16 GEMM: C = op(A @ Bt^T + bias), A/Bt in BLOCKED format ----------
// Round-8: round-2's 4-phase 256x256 schedule (lane-linear LDS, zero bank
// conflicts) + blocked global operands -> staging is contiguous 1KB/wave
// per g2l16 (was 32 scattered 16B granules; that scatter cost +20us in r2).
// blockedC=1 writes C in blocked format (feeds next gemm); =0 row-major.
__global__ __launch_bounds__(512, 2) void k_gemm(const u16* __restrict__ A, const u16* __restrict__ Bt,
                                                 const float* __restrict__ bias, u16* __restrict__ C,
                                                 int M, int N, int K, int relu, int blockedC) {
  __shared__ __align__(16) u16 sm[65536];  // 128 KiB
  const int tid = threadIdx.x;
  const int l = tid & 63, w = tid >> 6;
  const int wm = w >> 2, wn = w & 3;       // 2 (M) x 4 (N)
  const int lm = l & 31, c0 = l >> 5;
  const int m0 = blockIdx.y * 256, n0 = blockIdx.x * 256;

  // blocked staging bases: wave w owns row-group g = (m0|n0)/32 + w
  const char* gA = (const char*)A + (size_t)((m0 >> 5) + w) * 1024 + l * 16;
  const char* gB = (const char*)Bt + (size_t)((n0 >> 5) + w) * 1024 + l * 16;
  const size_t slabA = (size_t)M * 32, slabB = (size_t)N * 32;  // bytes per k16-slab

  auto issue_half = [&](int t, int part, int stg) {
    // part: 0 = A k-half0, 1 = B k-half0, 2 = A k-half1, 3 = B k-half1
    const int h = part >> 1, isB = part & 1;
    const char* g = isB ? gB : gA;
    const size_t slab = isB ? slabB : slabA;
    const int s0 = t * 4 + h * 2;
    char* lb = (char*)sm + stg * 65536 + isB * 32768 + h * 16384 + w * 1024 + l * 16;
    g2l16(g + (size_t)s0 * slab, lb);
    g2l16(g + (size_t)(s0 + 1) * slab, lb + 8192);
  };

  f32x16 acc[4][2] = {};
  const int NT = K >> 6;

  // prologue: tile 0's 4 half-tiles; vmcnt(4) -> K-half0 of A and B landed
  issue_half(0, 0, 0); issue_half(0, 1, 0); issue_half(0, 2, 0); issue_half(0, 3, 0);
  asm volatile("s_waitcnt vmcnt(4)" ::: "memory");
  asm volatile("s_barrier" ::: "memory");

  for (int kt = 0; kt < NT; ++kt) {
    const u16* bcur = sm + (kt & 1) * 32768;   // u16 units
    const int nstg = (kt & 1) ^ 1;
    const bool pf = (kt + 1) < NT;

#pragma unroll
    for (int k = 0; k < 4; ++k) {              // 4 phases, K=16 each
      const u16* As = bcur + (k >> 1) * 8192;           // A half-tile (u16 units)
      const u16* Bs = bcur + 16384 + (k >> 1) * 8192;   // B half-tile
      const int fb = (k & 1) * 4096 + c0 * 256 + lm * 8;  // lane-linear frag base
      bf16x8 a4[4], b2[2];
#pragma unroll
      for (int fm = 0; fm < 4; ++fm)
        a4[fm] = *(const bf16x8*)(As + fb + (wm * 4 + fm) * 512);
#pragma unroll
      for (int fn = 0; fn < 2; ++fn)
        b2[fn] = *(const bf16x8*)(Bs + fb + (wn * 2 + fn) * 512);
      if (pf) issue_half(kt + 1, k, nstg);
      asm volatile("s_barrier" ::: "memory");
      asm volatile("s_waitcnt lgkmcnt(0)" ::: "memory");
      __builtin_amdgcn_s_setprio(1);
#pragma unroll
      for (int fm = 0; fm < 4; ++fm)
#pragma unroll
        for (int fn = 0; fn < 2; ++fn)
          acc[fm][fn] = __builtin_amdgcn_mfma_f32_32x32x16_bf16(a4[fm], b2[fn],
                                                                acc[fm][fn], 0, 0, 0);
      __builtin_amdgcn_s_setprio(0);
      if (k & 1) {
        if (pf) asm volatile("s_waitcnt vmcnt(4)" ::: "memory");
        else    asm volatile("s_waitcnt vmcnt(0)" ::: "memory");
      }
      asm volatile("s_barrier" ::: "memory");
    }
  }

  if (blockedC) {
#pragma unroll
    for (int fn = 0; fn < 2; ++fn) {
      const int col = n0 + wn * 64 + lm + fn * 32;
      const float b = bias[col];
      const int sc = col >> 4, cb = (col >> 3) & 1, e = col & 7;
#pragma unroll
      for (int fm = 0; fm < 4; ++fm) {
        const int gg = (m0 >> 5) + wm * 4 + fm;
        u16* base = C + (size_t)sc * ((size_t)M * 16) + gg * 512 + cb * 256 + e;
#pragma unroll
        for (int g = 0; g < 4; ++g)
#pragma unroll
          for (int rr = 0; rr < 4; ++rr) {
            float v = acc[fm][fn][g * 4 + rr] + b;
            if (relu) v = fmaxf(v, 0.0f);
            base[(4 * c0 + g * 8 + rr) * 8] = f2bf(v);
          }
      }
    }
  } else {
    const int colb = n0 + wn * 64 + lm;
    const int rowb = m0 + wm * 128 + 4 * c0;
#pragma unroll
    for (int fn = 0; fn < 2; ++fn) {
      const float b = bias[colb + fn * 32];
#pragma unroll
      for (int fm = 0; fm < 4; ++fm)
#pragma unroll
        for (int g = 0; g < 4; ++g)
#pragma unroll
          for (int rr = 0; rr < 4; ++rr) {
            float v = acc[fm][fn][g * 4 + rr] + b;
            if (relu) v = fmaxf(v, 0.0f);
            C[(size_t)(rowb + fm * 32 + g * 8 + rr) * N + colb + fn * 32] = f2bf(v);
          }
    }
  }
}

// ---------- split-K GEMM2 (N=128): 128x128 tile, 3-stage, 1 barrier/step ----------
__global__ __launch_bounds__(256, 2) void k_gemm_sk(const u16* __restrict__ A, const u16* __restrict__ Bt,
                                                    float* __restrict__ Ep, int K, int Ksplit) {
  __shared__ __align__(16) u16 sm[24576];
  const int tid = threadIdx.x;
  const int l = tid & 63, w = tid >> 6;
  const int wm = w >> 1, wn = w & 1;
  const int m0 = blockIdx.y * 128;
  const int split = blockIdx.x;
  const int k0s = split * Ksplit;

  const int kb = ((l & 3) ^ ((l >> 3) & 3)) * 16;
  const char* gA = (const char*)(A + (size_t)(m0 + w * 16 + (l >> 2)) * K + k0s) + kb;
  const char* gB = (const char*)(Bt + (size_t)(w * 16 + (l >> 2)) * K + k0s) + kb;
  const size_t radv = (size_t)64 * K * 2;

  auto issue = [&](int kcB, int stg) {
    char* base = (char*)sm + stg * 16384;
    char* dA = base + w * 1024 + l * 16;
    char* dB = base + 8192 + w * 1024 + l * 16;
    g2l16(gA + kcB, dA);
    g2l16(gA + radv + kcB, dA + 4096);
    g2l16(gB + kcB, dB);
    g2l16(gB + radv + kcB, dB + 4096);
  };

  const int lm = l & 31;
  const int c0 = l >> 5;
  const int sw = (lm >> 1) & 3;

  f32x16 acc[2][2] = {};

  auto compute = [&](int stg) {
    const u16* As = sm + stg * 8192;
    const u16* Bs = As + 4096;
#pragma unroll
    for (int t = 0; t < 2; ++t) {
      const int cc = (((t << 1) + c0) ^ sw) * 8;
      bf16x8 a2[2], b2[2];
#pragma unroll
      for (int fm = 0; fm < 2; ++fm) a2[fm] = *(const bf16x8*)(As + (wm * 64 + fm * 32 + lm) * 32 + cc);
#pragma unroll
      for (int fn = 0; fn < 2; ++fn) b2[fn] = *(const bf16x8*)(Bs + (wn * 64 + fn * 32 + lm) * 32 + cc);
#pragma unroll
      for (int fm = 0; fm < 2; ++fm)
#pragma unroll
        for (int fn = 0; fn < 2; ++fn)
          acc[fm][fn] = __builtin_amdgcn_mfma_f32_32x32x16_bf16(a2[fm], b2[fn],
                                                                acc[fm][fn], 0, 0, 0);
    }
  };

  const int NK = Ksplit >> 5;
  issue(0, 0);
  issue(64, 1);
  int st = 0;
  for (int kt = 0; kt < NK; ++kt) {
    if (kt + 1 < NK) asm volatile("s_waitcnt vmcnt(4)" ::: "memory");
    else             asm volatile("s_waitcnt vmcnt(0)" ::: "memory");
    asm volatile("s_barrier" ::: "memory");
    if (kt + 2 < NK) {
      int stp = st + 2; if (stp >= 3) stp -= 3;
      issue((kt + 2) * 64, stp);
    }
    compute(st);
    ++st; if (st == 3) st = 0;
  }

  const int colb = wn * 64 + lm;
  const int rowb = m0 + wm * 64 + 4 * c0;
#pragma unroll
  for (int fn = 0; fn < 2; ++fn)
#pragma unroll
    for (int fm = 0; fm < 2; ++fm)
#pragma unroll
      for (int g = 0; g < 4; ++g)
#pragma unroll
        for (int rr = 0; rr < 4; ++rr)
          Ep[((size_t)split * 8192 + rowb + fm * 32 + g * 8 + rr) * 128 + colb + fn * 32] =
              acc[fm][fn][g * 4 + rr];
}

// ---------- sum split-K partials + bias, L2-normalize rows, write bf16 f ----------
__global__ __launch_bounds__(256) void k_norm(const float* __restrict__ Ep,
                                              const float* __restrict__ b2, u16* __restrict__ F) {
  const int l = threadIdx.x & 63, w = threadIdx.x >> 6;
  const int row = blockIdx.x * 4 + w;
  const float2* base = (const float2*)Ep + (size_t)row * 64 + l;
  float x = 0.f, y = 0.f;
#pragma unroll
  for (int s = 0; s < 4; ++s) {
    float2 t = base[(size_t)s * (8192 * 64)];
    x += t.x; y += t.y;
  }
  x += b2[l * 2]; y += b2[l * 2 + 1];
  float sq = x * x + y * y;
#pragma unroll
  for (int off = 1; off < 64; off <<= 1) sq += __shfl_xor(sq, off);
  const float inv = 1.0f / sqrtf(sq);
  F[(size_t)row * 128 + l * 2] = f2bf(x * inv);
  F[(size_t)row * 128 + l * 2 + 1] = f2bf(y * inv);
}

// ---------- fused sim GEMM + fixed-max sumexp, register-cached A ----------
__global__ __launch_bounds__(256, 2) void k_sim(const u16* __restrict__ F, float* __restrict__ Sp) {
  __shared__ __align__(16) u16 sm[32768];  // [B0 32KB][A/B1 32KB]
  const int tid = threadIdx.x;
  const int l = tid & 63, w = tid >> 6;
  const int wm = w >> 1, wn = w & 1;
  const int lm = l & 31, c0 = l >> 5;
  const int r0 = blockIdx.y * 128;
  const int cb0 = blockIdx.x * 1024;

  u16* B0 = sm;
  u16* AB1 = sm + 16384;

  const int srow0 = tid >> 4;
  const int schunk = tid & 15;
  auto stage = [&](const u16* src, u16* dst) {
#pragma unroll
    for (int j = 0; j < 8; ++j) {
      const int row = j * 16 + srow0;
      const int lc = schunk ^ (row & 7);
      g2l16((const char*)(src + (size_t)row * 128) + lc * 16,
            (char*)dst + j * 4096 + tid * 16);
    }
  };

  stage(F + (size_t)r0 * 128, AB1);
  asm volatile("s_waitcnt vmcnt(0)" ::: "memory");
  __syncthreads();

  bf16x8 a[2][8];
#pragma unroll
  for (int fm = 0; fm < 2; ++fm) {
    const int ra = wm * 64 + fm * 32 + lm;
#pragma unroll
    for (int kf = 0; kf < 8; ++kf)
      a[fm][kf] = *(const bf16x8*)(AB1 + ra * 128 + (((kf << 1) + c0) ^ (ra & 7)) * 8);
  }
  asm volatile("s_waitcnt lgkmcnt(0)" ::: "memory");

  stage(F + (size_t)cb0 * 128, B0);

  const float S2 = INVT * L2E;
  const int rB = wn * 64 + lm;
  f32x16 runS[2] = {};

#pragma unroll 1
  for (int p = 0; p < 8; ++p) {
    asm volatile("s_waitcnt vmcnt(0)" ::: "memory");
    asm volatile("s_barrier" ::: "memory");
    if (p < 7) stage(F + (size_t)(cb0 + (p + 1) * 128) * 128, (p & 1) ? B0 : AB1);
    const u16* Bs = (p & 1) ? AB1 : B0;

    f32x16 acc[2][2] = {};
#pragma unroll
    for (int kf = 0; kf < 8; ++kf) {
      const int kc = (kf << 1) + c0;
      bf16x8 b0v = *(const bf16x8*)(Bs + rB * 128 + (kc ^ (rB & 7)) * 8);
      bf16x8 b1v = *(const bf16x8*)(Bs + (rB + 32) * 128 + (kc ^ ((rB + 32) & 7)) * 8);
      acc[0][0] = __builtin_amdgcn_mfma_f32_32x32x16_bf16(a[0][kf], b0v, acc[0][0], 0, 0, 0);
      acc[0][1] = __builtin_amdgcn_mfma_f32_32x32x16_bf16(a[0][kf], b1v, acc[0][1], 0, 0, 0);
      acc[1][0] = __builtin_amdgcn_mfma_f32_32x32x16_bf16(a[1][kf], b0v, acc[1][0], 0, 0, 0);
      acc[1][1] = __builtin_amdgcn_mfma_f32_32x32x16_bf16(a[1][kf], b1v, acc[1][1], 0, 0, 0);
    }

    const int cp = cb0 + p * 128;
    if (cp == r0) {
#pragma unroll
      for (int fm = 0; fm < 2; ++fm)
#pragma unroll
        for (int fn = 0; fn < 2; ++fn) {
          const int rcol = wn * 64 + fn * 32 + lm;
#pragma unroll
          for (int r = 0; r < 16; ++r) {
            const int rrow = wm * 64 + fm * 32 + (r & 3) + 8 * (r >> 2) + 4 * c0;
            float e = exp2f(fmaf(acc[fm][fn][r], S2, -S2));
            if (rrow == rcol) e = 0.f;
            runS[fm][r] += e;
          }
        }
    } else {
#pragma unroll
      for (int fm = 0; fm < 2; ++fm)
#pragma unroll
        for (int fn = 0; fn < 2; ++fn)
#pragma unroll
          for (int r = 0; r < 16; ++r)
            runS[fm][r] += exp2f(fmaf(acc[fm][fn][r], S2, -S2));
    }
  }

#pragma unroll
  for (int fm = 0; fm < 2; ++fm)
#pragma unroll
    for (int r = 0; r < 16; ++r) {
      float s = runS[fm][r];
      s += __shfl_xor(s, 1);
      s += __shfl_xor(s, 2);
      s += __shfl_xor(s, 4);
      s += __shfl_xor(s, 8);
      s += __shfl_xor(s, 16);
      runS[fm][r] = s;
    }

  __syncthreads();
  float* red = (float*)sm;
  if (wn == 0) {
    if (lm == 0) {
#pragma unroll
      for (int fm = 0; fm < 2; ++fm)
#pragma unroll
        for (int r = 0; r < 16; ++r)
          red[wm * 64 + fm * 32 + (r & 3) + 8 * (r >> 2) + 4 * c0] = runS[fm][r];
    }
  }
  __syncthreads();
  if (wn == 1 && lm == 0) {
#pragma unroll
    for (int fm = 0; fm < 2; ++fm)
#pragma unroll
      for (int r = 0; r < 16; ++r) {
        const int rr = wm * 64 + fm * 32 + (r & 3) + 8 * (r >> 2) + 4 * c0;
        Sp[(size_t)blockIdx.x * 8192 + r0 + rr] = red[rr] + runS[fm][r];
      }
  }
}

// ---------- merge chunk partials, compute pos, reduce mean(lse - pos) ----------
__global__ __launch_bounds__(256) void k_combine(const float* __restrict__ Sp,
                                                 const u16* __restrict__ F,
                                                 float* __restrict__ out) {
  const int r = blockIdx.x * 256 + threadIdx.x;
  float S = 0.f;
#pragma unroll
  for (int c = 0; c < 8; ++c) S += Sp[c * 8192 + r];
  const float lse = INVT + logf(S);
  const int par = (r + 4096) & 8191;
  const bf16x8* a = (const bf16x8*)(F + (size_t)r * 128);
  const bf16x8* b = (const bf16x8*)(F + (size_t)par * 128);
  float dot = 0.f;
#pragma unroll
  for (int k = 0; k < 16; ++k) {
    bf16x8 va = a[k], vb = b[k];
#pragma unroll
    for (int j = 0; j < 8; ++j) dot = fmaf((float)va[j], (float)vb[j], dot);
  }
  float contrib = lse - dot * INVT;
#pragma unroll
  for (int off = 1; off < 64; off <<= 1) contrib += __shfl_xor(contrib, off);
  if ((threadIdx.x & 63) == 0) atomicAdd(out, contrib * (1.0f / 8192.0f));
}

extern "C" void kernel_launch(void* const* d_in, const int* in_sizes, int n_in,
                              void* d_out, int out_size, void* d_ws, size_t ws_size,
                              hipStream_t stream) {
  const float* input1 = (const float*)d_in[0];
  const float* input2 = (const float*)d_in[1];
  const float* W0 = (const float*)d_in[2];
  const float* b0 = (const float*)d_in[3];
  const float* W1 = (const float*)d_in[4];
  const float* b1 = (const float*)d_in[5];
  const float* W2 = (const float*)d_in[6];
  const float* b2 = (const float*)d_in[7];
  float* out = (float*)d_out;
  char* ws = (char*)d_ws;

  u16* Xb = (u16*)(ws + 0);              // [8192][2048] bf16 BLOCKED; reused as H2 (row-major)
  u16* H1 = (u16*)(ws + 33554432);       // BLOCKED
  u16* W0T = (u16*)(ws + 67108864);      // BLOCKED
  u16* W1T = (u16*)(ws + 75497472);      // BLOCKED
  float* Ep = (float*)(ws + 67108864);   // [4][8192][128] fp32, overlays dead W0T/W1T
  u16* W2T = (u16*)(ws + 83886080);      // row-major
  float* Sp = (float*)(ws + 83886080);   // [8][8192] fp32, overlays W2T after sk
  u16* Ff = (u16*)(ws + 84410368);
  u16* H2 = Xb;

  hipMemsetAsync(d_out, 0, sizeof(float), stream);
  k_prep<<<12352, 256, 0, stream>>>(input1, input2, Xb, W0, W0T, W1, W1T, W2, W2T);
  k_gemm<<<dim3(8, 32), 512, 0, stream>>>(Xb, W0T, b0, H1, 8192, 2048, 2048, 1, 1);
  k_gemm<<<dim3(8, 32), 512, 0, stream>>>(H1, W1T, b1, H2, 8192, 2048, 2048, 0, 0);
  k_gemm_sk<<<dim3(4, 64), 256, 0, stream>>>(H2, W2T, Ep, 2048, 512);
  k_norm<<<2048, 256, 0, stream>>>(Ep, b2, Ff);
  k_sim<<<dim3(8, 64), 256, 0, stream>>>(Ff, Sp);
  k_combine<<<32, 256, 0, stream>>>(Sp, Ff, out);
}

// Round 4
// 325.636 us; speedup vs baseline: 1.0749x; 1.0429x over previous
//
#include <hip/hip_runtime.h>
#include <stdint.h>

typedef float f32x4 __attribute__((ext_vector_type(4)));
typedef float f32x16 __attribute__((ext_vector_type(16)));
typedef __bf16 bf16x8 __attribute__((ext_vector_type(8)));
typedef unsigned short u16;
typedef unsigned int u32;

#define INVT 14.285714285714286f   // 1/0.07 ; also the fixed LSE max bound (cos<=1)
#define L2E  1.4426950408889634f

__device__ __forceinline__ u16 f2bf(float f) {
  u32 u = __float_as_uint(f);
  u32 r = (u + 0x7fffu + ((u >> 16) & 1u)) >> 16;
  return (u16)r;
}
__device__ __forceinline__ float bf2f(u16 h) { return __uint_as_float(((u32)h) << 16); }

// async global->LDS, 16B per lane (lane i lands at base + i*16)
__device__ __forceinline__ void g2l16(const void* g, void* l) {
  auto gp = reinterpret_cast<__attribute__((address_space(1))) uint32_t*>(
      reinterpret_cast<uintptr_t>(g));
  auto lp = reinterpret_cast<__attribute__((address_space(3))) uint32_t*>(
      reinterpret_cast<uintptr_t>(l));
  __builtin_amdgcn_global_load_lds(gp, lp, 16, 0, 0);
}

// ================= BLOCKED GLOBAL FORMAT =================
// For an MxK bf16 matrix (M mult of 32, K mult of 16):
//   elem (r, c) -> u16 offset  s*(M*16) + g*512 + c0*256 + lm*8 + e
//   with s = c>>4, g = r>>5, c0 = (c>>3)&1, lm = r&31, e = c&7.
// This is EXACTLY the k_gemm LDS image: staging is a contiguous 1KB/wave
// memcpy and fragment ds_reads are lane-linear (round-3 verified:
// SQ_LDS_BANK_CONFLICT == 0, staging coalesced).

// ---------- fused prep ----------
// [0,2048): cvt in1/in2 f32 -> Xb blocked bf16 via LDS bounce (r3's direct
//   version read 32B granules at 8KB stride = 2-4x over-fetch on 64MB; this
//   version reads 128B-coalesced rows and writes contiguous 1KB units).
// [2048,6144): W0/W1 direct transpose -> blocked W0T/W1T (reads already
//   128B-coalesced, writes lane-linear -- unchanged from r3).
// [6144,6208): W2 tile transpose -> row-major W2T (gemm_sk unchanged).
__global__ __launch_bounds__(256) void k_prep(const float* __restrict__ in1,
                                              const float* __restrict__ in2,
                                              u16* __restrict__ Xb,
                                              const float* __restrict__ w0, u16* __restrict__ w0t,
                                              const float* __restrict__ w1, u16* __restrict__ w1t,
                                              const float* __restrict__ w2, u16* __restrict__ w2t) {
  const int bid = blockIdx.x;
  const int tid = threadIdx.x;
  if (bid < 2048) {
    // block owns 64 rows x 128 cols; LDS tile [64][136] u16 (136: 16B-aligned rows)
    __shared__ u16 tl[64][136];
    const int rb = bid >> 4, cb = bid & 15;
    const int R0 = rb * 64, C0 = cb * 128;
    const float* src = (R0 < 4096 ? in1 : in2);
    const int Rs = (R0 < 4096 ? R0 : R0 - 4096);
    const int r = tid >> 2;
    const int cbase = (tid & 3) * 8;
#pragma unroll
    for (int p = 0; p < 4; ++p) {
      const int c = cbase + p * 32;
      const float* sp = src + (size_t)(Rs + r) * 2048 + C0 + c;
      float4 v0 = *(const float4*)sp;
      float4 v1 = *(const float4*)(sp + 4);
      u16* d = &tl[r][c];
      d[0] = f2bf(v0.x); d[1] = f2bf(v0.y); d[2] = f2bf(v0.z); d[3] = f2bf(v0.w);
      d[4] = f2bf(v1.x); d[5] = f2bf(v1.y); d[6] = f2bf(v1.z); d[7] = f2bf(v1.w);
    }
    __syncthreads();
    // write 16 blocked units (s in [0,8), g in [0,2)), 1KB contiguous each
    const int u = tid >> 4, t16 = tid & 15;
    const int g = u >> 3, s = u & 7;
    const int c0 = t16 >> 3, lmb = (t16 & 7) * 4;
    u16* dst = Xb + (size_t)(cb * 8 + s) * 131072 + (rb * 2 + g) * 512 + t16 * 32;
#pragma unroll
    for (int q = 0; q < 4; ++q)
      *(uint4*)(dst + q * 8) = *(const uint4*)&tl[g * 32 + lmb + q][s * 16 + c0 * 8];
    return;
  }
  if (bid < 6144) {
    // W (2048x2048 f32, row-major [k][n]) -> WT blocked over (n rows, k cols)
    const int l = tid & 63, w = tid >> 6;
    const int lm = l & 31, ch = l >> 5;
    const int v = (bid - 2048) * 4 + w;
    const int z = v >> 13, u2 = v & 8191;
    const int s = u2 & 127, g = u2 >> 7;     // s: k-slab, g in [0,64)
    const float* Wm = z ? w1 : w0;
    u16* O = z ? w1t : w0t;
    const float* src = Wm + (size_t)(s * 16 + ch * 8) * 2048 + g * 32 + lm;
    float f0 = src[0];
    float f1 = src[2048];
    float f2 = src[2 * 2048];
    float f3 = src[3 * 2048];
    float f4 = src[4 * 2048];
    float f5 = src[5 * 2048];
    float f6 = src[6 * 2048];
    float f7 = src[7 * 2048];
    uint4 o;
    o.x = (u32)f2bf(f0) | ((u32)f2bf(f1) << 16);
    o.y = (u32)f2bf(f2) | ((u32)f2bf(f3) << 16);
    o.z = (u32)f2bf(f4) | ((u32)f2bf(f5) << 16);
    o.w = (u32)f2bf(f6) | ((u32)f2bf(f7) << 16);
    *(uint4*)(O + (size_t)s * 32768 + g * 512 + l * 8) = o;
    return;
  }
  // W2 tile transpose (row-major out, unchanged consumer: k_gemm_sk)
  __shared__ float t[64][65];
  const int f = bid - 6144;
  const float* in = w2;
  u16* out = w2t;
  const int C = 128, R = 2048;
  const int r0 = (f >> 1) * 64, c0t = (f & 1) * 64;
#pragma unroll
  for (int p = 0; p < 16; ++p) {
    int idx = p * 256 + tid;
    int r = idx >> 6, c = idx & 63;
    t[r][c] = in[(size_t)(r0 + r) * C + (c0t + c)];
  }
  __syncthreads();
#pragma unroll
  for (int p = 0; p < 16; ++p) {
    int idx = p * 256 + tid;
    int c = idx >> 6, r = idx & 63;
    out[(size_t)(c0t + c) * R + (r0 + r)] = f2bf(t[r][c]);
  }
}

// ---------- bf16 GEMM: C = op(A @ Bt^T + bias), A/Bt in BLOCKED format ----------
// Round-9: r3 (lane-linear LDS, zero conflicts, coalesced staging) +
// (a) sched_barrier(0) pins per guide rule 18: without them hipcc hoists
//     the register-only MFMAs above the inline-asm lgkmcnt/s_barrier and
//     dissolves the phase structure (r0/r1/r3 all ~36% regardless of
//     schedule = compiler was picking its own order every time);
// (b) bijective XCD swizzle: linear%8 -> XCD; each XCD gets a 4x8 patch
//     (4 B-panels + 8 A-panels = 12MB vs 33MB unswizzled working set).
__global__ __launch_bounds__(512, 2) void k_gemm(const u16* __restrict__ A, const u16* __restrict__ Bt,
                                                 const float* __restrict__ bias, u16* __restrict__ C,
                                                 int M, int N, int K, int relu, int blockedC) {
  __shared__ __align__(16) u16 sm[65536];  // 128 KiB
  const int tid = threadIdx.x;
  const int l = tid & 63, w = tid >> 6;
  const int wm = w >> 2, wn = w & 3;       // 2 (M) x 4 (N)
  const int lm = l & 31, c0 = l >> 5;

  // XCD-aware bijective swizzle (grid must be 8 x 32)
  const int bid0 = blockIdx.y * 8 + blockIdx.x;
  const int xcd = bid0 & 7, slot = bid0 >> 3;
  const int bx = (xcd & 1) * 4 + (slot & 3);
  const int by = (xcd >> 1) * 8 + (slot >> 2);
  const int m0 = by * 256, n0 = bx * 256;

  // blocked staging bases: wave w owns row-group g = (m0|n0)/32 + w
  const char* gA = (const char*)A + (size_t)((m0 >> 5) + w) * 1024 + l * 16;
  const char* gB = (const char*)Bt + (size_t)((n0 >> 5) + w) * 1024 + l * 16;
  const size_t slabA = (size_t)M * 32, slabB = (size_t)N * 32;  // bytes per k16-slab

  auto issue_half = [&](int t, int part, int stg) {
    // part: 0 = A k-half0, 1 = B k-half0, 2 = A k-half1, 3 = B k-half1
    const int h = part >> 1, isB = part & 1;
    const char* g = isB ? gB : gA;
    const size_t slab = isB ? slabB : slabA;
    const int s0 = t * 4 + h * 2;
    char* lb = (char*)sm + stg * 65536 + isB * 32768 + h * 16384 + w * 1024 + l * 16;
    g2l16(g + (size_t)s0 * slab, lb);
    g2l16(g + (size_t)(s0 + 1) * slab, lb + 8192);
  };

  f32x16 acc[4][2] = {};
  const int NT = K >> 6;

  // prologue: tile 0's 4 half-tiles; vmcnt(4) -> K-half0 of A and B landed
  issue_half(0, 0, 0); issue_half(0, 1, 0); issue_half(0, 2, 0); issue_half(0, 3, 0);
  asm volatile("s_waitcnt vmcnt(4)" ::: "memory");
  asm volatile("s_barrier" ::: "memory");

  for (int kt = 0; kt < NT; ++kt) {
    const u16* bcur = sm + (kt & 1) * 32768;   // u16 units
    const int nstg = (kt & 1) ^ 1;
    const bool pf = (kt + 1) < NT;

#pragma unroll
    for (int k = 0; k < 4; ++k) {              // 4 phases, K=16 each
      const u16* As = bcur + (k >> 1) * 8192;           // A half-tile (u16 units)
      const u16* Bs = bcur + 16384 + (k >> 1) * 8192;   // B half-tile
      const int fb = (k & 1) * 4096 + c0 * 256 + lm * 8;  // lane-linear frag base
      bf16x8 a4[4], b2[2];
#pragma unroll
      for (int fm = 0; fm < 4; ++fm)
        a4[fm] = *(const bf16x8*)(As + fb + (wm * 4 + fm) * 512);
#pragma unroll
      for (int fn = 0; fn < 2; ++fn)
        b2[fn] = *(const bf16x8*)(Bs + fb + (wn * 2 + fn) * 512);
      if (pf) issue_half(kt + 1, k, nstg);
      asm volatile("s_barrier" ::: "memory");
      asm volatile("s_waitcnt lgkmcnt(0)" ::: "memory");
      __builtin_amdgcn_sched_barrier(0);       // rule 18: pin MFMA below the wait
      __builtin_amdgcn_s_setprio(1);
#pragma unroll
      for (int fm = 0; fm < 4; ++fm)
#pragma unroll
        for (int fn = 0; fn < 2; ++fn)
          acc[fm][fn] = __builtin_amdgcn_mfma_f32_32x32x16_bf16(a4[fm], b2[fn],
                                                                acc[fm][fn], 0, 0, 0);
      __builtin_amdgcn_s_setprio(0);
      __builtin_amdgcn_sched_barrier(0);       // keep the MFMA cluster intact
      if (k & 1) {
        if (pf) asm volatile("s_waitcnt vmcnt(4)" ::: "memory");
        else    asm volatile("s_waitcnt vmcnt(0)" ::: "memory");
      }
      asm volatile("s_barrier" ::: "memory");
    }
  }

  if (blockedC) {
#pragma unroll
    for (int fn = 0; fn < 2; ++fn) {
      const int col = n0 + wn * 64 + lm + fn * 32;
      const float b = bias[col];
      const int sc = col >> 4, cb = (col >> 3) & 1, e = col & 7;
#pragma unroll
      for (int fm = 0; fm < 4; ++fm) {
        const int gg = (m0 >> 5) + wm * 4 + fm;
        u16* base = C + (size_t)sc * ((size_t)M * 16) + gg * 512 + cb * 256 + e;
#pragma unroll
        for (int g = 0; g < 4; ++g)
#pragma unroll
          for (int rr = 0; rr < 4; ++rr) {
            float v = acc[fm][fn][g * 4 + rr] + b;
            if (relu) v = fmaxf(v, 0.0f);
            base[(4 * c0 + g * 8 + rr) * 8] = f2bf(v);
          }
      }
    }
  } else {
    const int colb = n0 + wn * 64 + lm;
    const int rowb = m0 + wm * 128 + 4 * c0;
#pragma unroll
    for (int fn = 0; fn < 2; ++fn) {
      const float b = bias[colb + fn * 32];
#pragma unroll
      for (int fm = 0; fm < 4; ++fm)
#pragma unroll
        for (int g = 0; g < 4; ++g)
#pragma unroll
          for (int rr = 0; rr < 4; ++rr) {
            float v = acc[fm][fn][g * 4 + rr] + b;
            if (relu) v = fmaxf(v, 0.0f);
            C[(size_t)(rowb + fm * 32 + g * 8 + rr) * N + colb + fn * 32] = f2bf(v);
          }
    }
  }
}

// ---------- split-K GEMM2 (N=128): 128x128 tile, 3-stage, 1 barrier/step ----------
__global__ __launch_bounds__(256, 2) void k_gemm_sk(const u16* __restrict__ A, const u16* __restrict__ Bt,
                                                    float* __restrict__ Ep, int K, int Ksplit) {
  __shared__ __align__(16) u16 sm[24576];
  const int tid = threadIdx.x;
  const int l = tid & 63, w = tid >> 6;
  const int wm = w >> 1, wn = w & 1;
  const int m0 = blockIdx.y * 128;
  const int split = blockIdx.x;
  const int k0s = split * Ksplit;

  const int kb = ((l & 3) ^ ((l >> 3) & 3)) * 16;
  const char* gA = (const char*)(A + (size_t)(m0 + w * 16 + (l >> 2)) * K + k0s) + kb;
  const char* gB = (const char*)(Bt + (size_t)(w * 16 + (l >> 2)) * K + k0s) + kb;
  const size_t radv = (size_t)64 * K * 2;

  auto issue = [&](int kcB, int stg) {
    char* base = (char*)sm + stg * 16384;
    char* dA = base + w * 1024 + l * 16;
    char* dB = base + 8192 + w * 1024 + l * 16;
    g2l16(gA + kcB, dA);
    g2l16(gA + radv + kcB, dA + 4096);
    g2l16(gB + kcB, dB);
    g2l16(gB + radv + kcB, dB + 4096);
  };

  const int lm = l & 31;
  const int c0 = l >> 5;
  const int sw = (lm >> 1) & 3;

  f32x16 acc[2][2] = {};

  auto compute = [&](int stg) {
    const u16* As = sm + stg * 8192;
    const u16* Bs = As + 4096;
#pragma unroll
    for (int t = 0; t < 2; ++t) {
      const int cc = (((t << 1) + c0) ^ sw) * 8;
      bf16x8 a2[2], b2[2];
#pragma unroll
      for (int fm = 0; fm < 2; ++fm) a2[fm] = *(const bf16x8*)(As + (wm * 64 + fm * 32 + lm) * 32 + cc);
#pragma unroll
      for (int fn = 0; fn < 2; ++fn) b2[fn] = *(const bf16x8*)(Bs + (wn * 64 + fn * 32 + lm) * 32 + cc);
#pragma unroll
      for (int fm = 0; fm < 2; ++fm)
#pragma unroll
        for (int fn = 0; fn < 2; ++fn)
          acc[fm][fn] = __builtin_amdgcn_mfma_f32_32x32x16_bf16(a2[fm], b2[fn],
                                                                acc[fm][fn], 0, 0, 0);
    }
  };

  const int NK = Ksplit >> 5;
  issue(0, 0);
  issue(64, 1);
  int st = 0;
  for (int kt = 0; kt < NK; ++kt) {
    if (kt + 1 < NK) asm volatile("s_waitcnt vmcnt(4)" ::: "memory");
    else             asm volatile("s_waitcnt vmcnt(0)" ::: "memory");
    asm volatile("s_barrier" ::: "memory");
    if (kt + 2 < NK) {
      int stp = st + 2; if (stp >= 3) stp -= 3;
      issue((kt + 2) * 64, stp);
    }
    compute(st);
    ++st; if (st == 3) st = 0;
  }

  const int colb = wn * 64 + lm;
  const int rowb = m0 + wm * 64 + 4 * c0;
#pragma unroll
  for (int fn = 0; fn < 2; ++fn)
#pragma unroll
    for (int fm = 0; fm < 2; ++fm)
#pragma unroll
      for (int g = 0; g < 4; ++g)
#pragma unroll
        for (int rr = 0; rr < 4; ++rr)
          Ep[((size_t)split * 8192 + rowb + fm * 32 + g * 8 + rr) * 128 + colb + fn * 32] =
              acc[fm][fn][g * 4 + rr];
}

// ---------- sum split-K partials + bias, L2-normalize rows, write bf16 f ----------
__global__ __launch_bounds__(256) void k_norm(const float* __restrict__ Ep,
                                              const float* __restrict__ b2, u16* __restrict__ F) {
  const int l = threadIdx.x & 63, w = threadIdx.x >> 6;
  const int row = blockIdx.x * 4 + w;
  const float2* base = (const float2*)Ep + (size_t)row * 64 + l;
  float x = 0.f, y = 0.f;
#pragma unroll
  for (int s = 0; s < 4; ++s) {
    float2 t = base[(size_t)s * (8192 * 64)];
    x += t.x; y += t.y;
  }
  x += b2[l * 2]; y += b2[l * 2 + 1];
  float sq = x * x + y * y;
#pragma unroll
  for (int off = 1; off < 64; off <<= 1) sq += __shfl_xor(sq, off);
  const float inv = 1.0f / sqrtf(sq);
  F[(size_t)row * 128 + l * 2] = f2bf(x * inv);
  F[(size_t)row * 128 + l * 2 + 1] = f2bf(y * inv);
}

// ---------- fused sim GEMM + fixed-max sumexp, register-cached A ----------
__global__ __launch_bounds__(256, 2) void k_sim(const u16* __restrict__ F, float* __restrict__ Sp) {
  __shared__ __align__(16) u16 sm[32768];  // [B0 32KB][A/B1 32KB]
  const int tid = threadIdx.x;
  const int l = tid & 63, w = tid >> 6;
  const int wm = w >> 1, wn = w & 1;
  const int lm = l & 31, c0 = l >> 5;
  const int r0 = blockIdx.y * 128;
  const int cb0 = blockIdx.x * 1024;

  u16* B0 = sm;
  u16* AB1 = sm + 16384;

  const int srow0 = tid >> 4;
  const int schunk = tid & 15;
  auto stage = [&](const u16* src, u16* dst) {
#pragma unroll
    for (int j = 0; j < 8; ++j) {
      const int row = j * 16 + srow0;
      const int lc = schunk ^ (row & 7);
      g2l16((const char*)(src + (size_t)row * 128) + lc * 16,
            (char*)dst + j * 4096 + tid * 16);
    }
  };

  stage(F + (size_t)r0 * 128, AB1);
  asm volatile("s_waitcnt vmcnt(0)" ::: "memory");
  __syncthreads();

  bf16x8 a[2][8];
#pragma unroll
  for (int fm = 0; fm < 2; ++fm) {
    const int ra = wm * 64 + fm * 32 + lm;
#pragma unroll
    for (int kf = 0; kf < 8; ++kf)
      a[fm][kf] = *(const bf16x8*)(AB1 + ra * 128 + (((kf << 1) + c0) ^ (ra & 7)) * 8);
  }
  asm volatile("s_waitcnt lgkmcnt(0)" ::: "memory");

  stage(F + (size_t)cb0 * 128, B0);

  const float S2 = INVT * L2E;
  const int rB = wn * 64 + lm;
  f32x16 runS[2] = {};

#pragma unroll 1
  for (int p = 0; p < 8; ++p) {
    asm volatile("s_waitcnt vmcnt(0)" ::: "memory");
    asm volatile("s_barrier" ::: "memory");
    if (p < 7) stage(F + (size_t)(cb0 + (p + 1) * 128) * 128, (p & 1) ? B0 : AB1);
    const u16* Bs = (p & 1) ? AB1 : B0;

    f32x16 acc[2][2] = {};
#pragma unroll
    for (int kf = 0; kf < 8; ++kf) {
      const int kc = (kf << 1) + c0;
      bf16x8 b0v = *(const bf16x8*)(Bs + rB * 128 + (kc ^ (rB & 7)) * 8);
      bf16x8 b1v = *(const bf16x8*)(Bs + (rB + 32) * 128 + (kc ^ ((rB + 32) & 7)) * 8);
      acc[0][0] = __builtin_amdgcn_mfma_f32_32x32x16_bf16(a[0][kf], b0v, acc[0][0], 0, 0, 0);
      acc[0][1] = __builtin_amdgcn_mfma_f32_32x32x16_bf16(a[0][kf], b1v, acc[0][1], 0, 0, 0);
      acc[1][0] = __builtin_amdgcn_mfma_f32_32x32x16_bf16(a[1][kf], b0v, acc[1][0], 0, 0, 0);
      acc[1][1] = __builtin_amdgcn_mfma_f32_32x32x16_bf16(a[1][kf], b1v, acc[1][1], 0, 0, 0);
    }

    const int cp = cb0 + p * 128;
    if (cp == r0) {
#pragma unroll
      for (int fm = 0; fm < 2; ++fm)
#pragma unroll
        for (int fn = 0; fn < 2; ++fn) {
          const int rcol = wn * 64 + fn * 32 + lm;
#pragma unroll
          for (int r = 0; r < 16; ++r) {
            const int rrow = wm * 64 + fm * 32 + (r & 3) + 8 * (r >> 2) + 4 * c0;
            float e = exp2f(fmaf(acc[fm][fn][r], S2, -S2));
            if (rrow == rcol) e = 0.f;
            runS[fm][r] += e;
          }
        }
    } else {
#pragma unroll
      for (int fm = 0; fm < 2; ++fm)
#pragma unroll
        for (int fn = 0; fn < 2; ++fn)
#pragma unroll
          for (int r = 0; r < 16; ++r)
            runS[fm][r] += exp2f(fmaf(acc[fm][fn][r], S2, -S2));
    }
  }

#pragma unroll
  for (int fm = 0; fm < 2; ++fm)
#pragma unroll
    for (int r = 0; r < 16; ++r) {
      float s = runS[fm][r];
      s += __shfl_xor(s, 1);
      s += __shfl_xor(s, 2);
      s += __shfl_xor(s, 4);
      s += __shfl_xor(s, 8);
      s += __shfl_xor(s, 16);
      runS[fm][r] = s;
    }

  __syncthreads();
  float* red = (float*)sm;
  if (wn == 0) {
    if (lm == 0) {
#pragma unroll
      for (int fm = 0; fm < 2; ++fm)
#pragma unroll
        for (int r = 0; r < 16; ++r)
          red[wm * 64 + fm * 32 + (r & 3) + 8 * (r >> 2) + 4 * c0] = runS[fm][r];
    }
  }
  __syncthreads();
  if (wn == 1 && lm == 0) {
#pragma unroll
    for (int fm = 0; fm < 2; ++fm)
#pragma unroll
      for (int r = 0; r < 16; ++r) {
        const int rr = wm * 64 + fm * 32 + (r & 3) + 8 * (r >> 2) + 4 * c0;
        Sp[(size_t)blockIdx.x * 8192 + r0 + rr] = red[rr] + runS[fm][r];
      }
  }
}

// ---------- merge chunk partials, compute pos, reduce mean(lse - pos) ----------
__global__ __launch_bounds__(256) void k_combine(const float* __restrict__ Sp,
                                                 const u16* __restrict__ F,
                                                 float* __restrict__ out) {
  const int r = blockIdx.x * 256 + threadIdx.x;
  float S = 0.f;
#pragma unroll
  for (int c = 0; c < 8; ++c) S += Sp[c * 8192 + r];
  const float lse = INVT + logf(S);
  const int par = (r + 4096) & 8191;
  const bf16x8* a = (const bf16x8*)(F + (size_t)r * 128);
  const bf16x8* b = (const bf16x8*)(F + (size_t)par * 128);
  float dot = 0.f;
#pragma unroll
  for (int k = 0; k < 16; ++k) {
    bf16x8 va = a[k], vb = b[k];
#pragma unroll
    for (int j = 0; j < 8; ++j) dot = fmaf((float)va[j], (float)vb[j], dot);
  }
  float contrib = lse - dot * INVT;
#pragma unroll
  for (int off = 1; off < 64; off <<= 1) contrib += __shfl_xor(contrib, off);
  if ((threadIdx.x & 63) == 0) atomicAdd(out, contrib * (1.0f / 8192.0f));
}

extern "C" void kernel_launch(void* const* d_in, const int* in_sizes, int n_in,
                              void* d_out, int out_size, void* d_ws, size_t ws_size,
                              hipStream_t stream) {
  const float* input1 = (const float*)d_in[0];
  const float* input2 = (const float*)d_in[1];
  const float* W0 = (const float*)d_in[2];
  const float* b0 = (const float*)d_in[3];
  const float* W1 = (const float*)d_in[4];
  const float* b1 = (const float*)d_in[5];
  const float* W2 = (const float*)d_in[6];
  const float* b2 = (const float*)d_in[7];
  float* out = (float*)d_out;
  char* ws = (char*)d_ws;

  u16* Xb = (u16*)(ws + 0);              // [8192][2048] bf16 BLOCKED; reused as H2 (row-major)
  u16* H1 = (u16*)(ws + 33554432);       // BLOCKED
  u16* W0T = (u16*)(ws + 67108864);      // BLOCKED
  u16* W1T = (u16*)(ws + 75497472);      // BLOCKED
  float* Ep = (float*)(ws + 67108864);   // [4][8192][128] fp32, overlays dead W0T/W1T
  u16* W2T = (u16*)(ws + 83886080);      // row-major
  float* Sp = (float*)(ws + 83886080);   // [8][8192] fp32, overlays W2T after sk
  u16* Ff = (u16*)(ws + 84410368);
  u16* H2 = Xb;

  hipMemsetAsync(d_out, 0, sizeof(float), stream);
  k_prep<<<6208, 256, 0, stream>>>(input1, input2, Xb, W0, W0T, W1, W1T, W2, W2T);
  k_gemm<<<dim3(8, 32), 512, 0, stream>>>(Xb, W0T, b0, H1, 8192, 2048, 2048, 1, 1);
  k_gemm<<<dim3(8, 32), 512, 0, stream>>>(H1, W1T, b1, H2, 8192, 2048, 2048, 0, 0);
  k_gemm_sk<<<dim3(4, 64), 256, 0, stream>>>(H2, W2T, Ep, 2048, 512);
  k_norm<<<2048, 256, 0, stream>>>(Ep, b2, Ff);
  k_sim<<<dim3(8, 64), 256, 0, stream>>>(Ff, Sp);
  k_combine<<<32, 256, 0, stream>>>(Sp, Ff, out);
}